// Round 1
// 313.197 us; speedup vs baseline: 1.0082x; 1.0082x over previous
//
#include <hip/hip_runtime.h>
#include <float.h>
#include <math.h>

// Problem constants (from reference setup_inputs)
#define B_   32
#define D_   128
#define T_   2048
#define K_   2048
#define N_   (B_ * T_)      // 65536

typedef _Float16 f16;
typedef f16   f16x8 __attribute__((ext_vector_type(8)));
typedef f16   f16x4 __attribute__((ext_vector_type(4)));
typedef f16   f16x2 __attribute__((ext_vector_type(2)));
typedef float f32x4 __attribute__((ext_vector_type(4)));

// async global->LDS, 16 B per lane, LDS dst = wave-uniform base + lane*16
__device__ __forceinline__ void load_lds16(const void* g, void* l) {
    __builtin_amdgcn_global_load_lds(
        (const __attribute__((address_space(1))) unsigned int*)g,
        (__attribute__((address_space(3))) unsigned int*)l, 16, 0, 0);
}

// ---------------------------------------------------------------------------
// emb -> (eh, el) fp16 split + halfnorm. One wave per code.
// Also zeroes cnt[k], sum_new[k][:], and the 3 scalar accumulators.
// ---------------------------------------------------------------------------
__global__ void eprep_kernel(const float* __restrict__ emb, f16* __restrict__ eh,
                             f16* __restrict__ el, float* __restrict__ hn,
                             int* __restrict__ cnt, float* __restrict__ scalars,
                             float* __restrict__ sum_new) {
    int k = blockIdx.x;
    int l = threadIdx.x;            // 64
    if (l == 0) cnt[k] = 0;
    if (k == 0 && l < 3) scalars[l] = 0.0f;
    sum_new[(size_t)k * D_ + l]      = 0.0f;
    sum_new[(size_t)k * D_ + 64 + l] = 0.0f;
    float a = emb[(size_t)k * D_ + l];
    float b = emb[(size_t)k * D_ + 64 + l];
    f16 ah = (f16)a; f16 al = (f16)(a - (float)ah);
    f16 bh = (f16)b; f16 bl = (f16)(b - (float)bh);
    eh[(size_t)k * D_ + l]      = ah;
    eh[(size_t)k * D_ + 64 + l] = bh;
    el[(size_t)k * D_ + l]      = al;
    el[(size_t)k * D_ + 64 + l] = bl;
    float s = a * a + b * b;
#pragma unroll
    for (int off = 32; off > 0; off >>= 1) s += __shfl_down(s, off, 64);
    if (l == 0) hn[k] = 0.5f * s;
}

// ---------------------------------------------------------------------------
// z [B,D,T] -> row-major fp16 split zh[N][D], zl[N][D] (transpose via LDS)
// ---------------------------------------------------------------------------
__global__ __launch_bounds__(256)
void prep_kernel(const float* __restrict__ z, f16* __restrict__ zh, f16* __restrict__ zl) {
    __shared__ float tile[64][129];
    const int tid = threadIdx.x;
    const int blk = blockIdx.x;              // 1024
    const int b   = blk >> 5;
    const int t0  = (blk & 31) * 64;
    const int n0  = b * T_ + t0;
    const float* zb = z + (size_t)b * D_ * T_ + t0;
#pragma unroll
    for (int it = 0; it < 8; it++) {
        int flat = it * 256 + tid;           // 128 d x 16 q
        int d = flat >> 4;
        int q = flat & 15;
        float4 zv = *(const float4*)(zb + (size_t)d * T_ + q * 4);
        tile[q * 4 + 0][d] = zv.x;
        tile[q * 4 + 1][d] = zv.y;
        tile[q * 4 + 2][d] = zv.z;
        tile[q * 4 + 3][d] = zv.w;
    }
    __syncthreads();
#pragma unroll
    for (int it = 0; it < 8; it++) {
        int r  = it * 8 + (tid >> 5);
        int d0 = (tid & 31) * 4;
        f16x4 hv, lv;
#pragma unroll
        for (int j = 0; j < 4; j++) {
            float v = tile[r][d0 + j];
            f16 hh = (f16)v;
            f16 ll = (f16)(v - (float)hh);
            if (j == 0) { hv.x = hh; lv.x = ll; }
            if (j == 1) { hv.y = hh; lv.y = ll; }
            if (j == 2) { hv.z = hh; lv.z = ll; }
            if (j == 3) { hv.w = hh; lv.w = ll; }
        }
        *(f16x4*)&zh[(size_t)(n0 + r) * D_ + d0] = hv;
        *(f16x4*)&zl[(size_t)(n0 + r) * D_ + d0] = lv;
    }
}

// ---------------------------------------------------------------------------
// MFMA distance-argmin, pipelined (T3+T4-lite):
//   A (zh+zl, 32 rows x 128 k per wave) lives ENTIRELY in registers
//   (16 f16x8 = 64 VGPR), loaded once — no A staging, no A LDS reads.
//   B = 64-code tiles {eh[64][128], el[64][128]} = 32 KB, DOUBLE-BUFFERED
//   (64 KB LDS -> 2 blocks/CU). Per tile: issue 8 global_load_lds for tile
//   t+1, s_waitcnt vmcnt(8) (tile t landed, t+1 stays IN FLIGHT across the
//   barrier), raw s_barrier, 16 ds_read_b128 -> 48 MFMA, raw s_barrier.
//   Never vmcnt(0) in the loop (peeled last iter only). hn prefetched one
//   tile ahead BEFORE the stage issue so compiler use-waits never drain.
// Wave grid 2Mx2N: wave owns 32 rows x 32 codes; dot = zh.eh + zl.eh + zh.el.
// ---------------------------------------------------------------------------
__global__ __launch_bounds__(256, 2)
void argmin_mfma(const f16* __restrict__ zh, const f16* __restrict__ zl,
                 const f16* __restrict__ eh, const f16* __restrict__ el,
                 const float* __restrict__ hn,
                 int* __restrict__ idx, int* __restrict__ cnt, int* __restrict__ pos) {
    __shared__ __align__(16) f16 BS[2][2][64 * 128];   // [buf][eh|el][code][k] = 64 KB

    const int tid = threadIdx.x;
    const int w   = tid >> 6;            // wave 0..3
    const int l   = tid & 63;
    const int wm  = w >> 1;              // M-half: rows wm*32..
    const int wn  = w & 1;               // N-half: codes wn*32.. of 64-code tile
    const int n0  = blockIdx.x * 64;     // 1024 blocks
    const int c15 = l & 15;
    const int q   = l >> 4;

    // ---- prologue: hn(tile0) -> regs, stage tile0, A -> regs ----
    float hc0 = hn[wn * 32 + c15];
    float hc1 = hn[wn * 32 + 16 + c15];

    {   // stage tile 0 into buf 0 (8 load_lds16/wave; XOR-16 swizzled source)
#pragma unroll
        for (int i = 0; i < 4; i++) {
            int cl = w * 16 + i * 4 + q;
            int g  = c15 ^ (cl & 15);
            load_lds16(eh + (size_t)cl * D_ + g * 8, &BS[0][0][(w * 16 + i * 4) * 128]);
            load_lds16(el + (size_t)cl * D_ + g * 8, &BS[0][1][(w * 16 + i * 4) * 128]);
        }
    }

    // A fragments: row = n0 + wm*32 + mi*16 + c15, k = s*32 + q*8 + j
    f16x8 azh[2][4], azl[2][4];
#pragma unroll
    for (int mi = 0; mi < 2; mi++)
#pragma unroll
        for (int s = 0; s < 4; s++) {
            size_t off = (size_t)(n0 + wm * 32 + mi * 16 + c15) * D_ + s * 32 + q * 8;
            azh[mi][s] = *(const f16x8*)&zh[off];
            azl[mi][s] = *(const f16x8*)&zl[off];
        }

    float minv[2][4];
    int   mini[2][4];
#pragma unroll
    for (int mi = 0; mi < 2; mi++)
#pragma unroll
        for (int r = 0; r < 4; r++) { minv[mi][r] = FLT_MAX; mini[mi][r] = 0x7fffffff; }

    for (int t = 0; t < 32; t++) {
        const int cur = t & 1;
        float hp0 = 0.0f, hp1 = 0.0f;
        if (t < 31) {
            // hn prefetch FIRST (older than the stage loads -> covered by vmcnt(8))
            hp0 = hn[(t + 1) * 64 + wn * 32 + c15];
            hp1 = hn[(t + 1) * 64 + wn * 32 + 16 + c15];
#pragma unroll
            for (int i = 0; i < 4; i++) {
                int cl = w * 16 + i * 4 + q;
                int g  = c15 ^ (cl & 15);
                load_lds16(eh + ((size_t)(t + 1) * 64 + cl) * D_ + g * 8,
                           &BS[cur ^ 1][0][(w * 16 + i * 4) * 128]);
                load_lds16(el + ((size_t)(t + 1) * 64 + cl) * D_ + g * 8,
                           &BS[cur ^ 1][1][(w * 16 + i * 4) * 128]);
            }
            // tile t's 8 loads (+ hn + A on t==0) done; tile t+1's 8 stay in flight
            asm volatile("s_waitcnt vmcnt(8)" ::: "memory");
        } else {
            asm volatile("s_waitcnt vmcnt(0)" ::: "memory");
        }
        __builtin_amdgcn_s_barrier();
        asm volatile("" ::: "memory");   // keep ds_reads below the barrier

        f32x4 acc[2][2];
#pragma unroll
        for (int mi = 0; mi < 2; mi++)
#pragma unroll
            for (int ni = 0; ni < 2; ni++) acc[mi][ni] = (f32x4){0.f, 0.f, 0.f, 0.f};

        const f16* __restrict__ BH = &BS[cur][0][0];
        const f16* __restrict__ BL = &BS[cur][1][0];
#pragma unroll
        for (int s = 0; s < 4; s++) {
            const int gp = (s * 4 + q) ^ c15;
            f16x8 bh[2], bl[2];
#pragma unroll
            for (int ni = 0; ni < 2; ni++) {
                int n = wn * 32 + ni * 16 + c15;
                bh[ni] = *(const f16x8*)&BH[n * 128 + gp * 8];
                bl[ni] = *(const f16x8*)&BL[n * 128 + gp * 8];
            }
#pragma unroll
            for (int mi = 0; mi < 2; mi++)
#pragma unroll
                for (int ni = 0; ni < 2; ni++) {
                    acc[mi][ni] = __builtin_amdgcn_mfma_f32_16x16x32_f16(
                        azh[mi][s], bh[ni], acc[mi][ni], 0, 0, 0);
                    acc[mi][ni] = __builtin_amdgcn_mfma_f32_16x16x32_f16(
                        azl[mi][s], bh[ni], acc[mi][ni], 0, 0, 0);
                    acc[mi][ni] = __builtin_amdgcn_mfma_f32_16x16x32_f16(
                        azh[mi][s], bl[ni], acc[mi][ni], 0, 0, 0);
                }
        }

        // ---- running argmin (codes ascend: t, ni ascending; strict <) ----
        const int k0 = t * 64;
#pragma unroll
        for (int ni = 0; ni < 2; ni++) {
            int   k = k0 + wn * 32 + ni * 16 + c15;
            float h = ni ? hc1 : hc0;
#pragma unroll
            for (int mi = 0; mi < 2; mi++)
#pragma unroll
                for (int r = 0; r < 4; r++) {
                    float sc = h - acc[mi][ni][r];
                    if (sc < minv[mi][r]) { minv[mi][r] = sc; mini[mi][r] = k; }
                }
        }
        hc0 = hp0; hc1 = hp1;

        asm volatile("" ::: "memory");   // keep ds_reads above this barrier
        __builtin_amdgcn_s_barrier();    // buf[cur] free for overwrite next iter
    }

    // ---- single epilogue: cross-lane reduce, write idx + count atomic ----
    __syncthreads();                     // full drain once; alias BS as red
    float* redv = (float*)&BS[0][0][0];  // [64][2]
    int*   redi = (int*)&BS[0][1][0];
#pragma unroll
    for (int mi = 0; mi < 2; mi++)
#pragma unroll
        for (int r = 0; r < 4; r++) {
            float bv = minv[mi][r];
            int   bi = mini[mi][r];
#pragma unroll
            for (int msk = 1; msk < 16; msk <<= 1) {
                float ov = __shfl_xor(bv, msk, 64);
                int   oi = __shfl_xor(bi, msk, 64);
                if (ov < bv || (ov == bv && oi < bi)) { bv = ov; bi = oi; }
            }
            if (c15 == 0) {
                int row = wm * 32 + mi * 16 + q * 4 + r;
                redv[row * 2 + wn] = bv;
                redi[row * 2 + wn] = bi;
            }
        }
    __syncthreads();
    if (tid < 64) {
        float v0 = redv[tid * 2 + 0]; int i0 = redi[tid * 2 + 0];
        float v1 = redv[tid * 2 + 1]; int i1 = redi[tid * 2 + 1];
        if (v1 < v0 || (v1 == v0 && i1 < i0)) { v0 = v1; i0 = i1; }
        int n = n0 + tid;
        idx[n] = i0;
        pos[n] = atomicAdd(&cnt[i0], 1);     // fused assign_kernel
    }
}

// ---------------------------------------------------------------------------
// STE output + loss (blocks 0..1023) with the single-block prefix-scan fused
// as block 1024 (removes the whole-GPU-idle scan launch). Scan only needs
// cnt (argmin done); ste only needs idx.
// ---------------------------------------------------------------------------
__global__ __launch_bounds__(256)
void ste_scan_kernel(const float* __restrict__ z, const float* __restrict__ emb,
                     const int* __restrict__ idx, float* __restrict__ out0,
                     float* __restrict__ s_loss,
                     const int* __restrict__ cnt, int* __restrict__ offs) {
    __shared__ int   scode[64];
    __shared__ float red[256];
    __shared__ int   part[256];
    const int tid = threadIdx.x;

    if (blockIdx.x == 1024) {            // ---- fused exclusive prefix scan ----
        int loc[8];
        int s = 0;
#pragma unroll
        for (int j = 0; j < 8; j++) { loc[j] = s; s += cnt[tid * 8 + j]; }
        part[tid] = s;
        __syncthreads();
        for (int off = 1; off < 256; off <<= 1) {
            int v = (tid >= off) ? part[tid - off] : 0;
            __syncthreads();
            part[tid] += v;
            __syncthreads();
        }
        int pre = (tid == 0) ? 0 : part[tid - 1];
#pragma unroll
        for (int j = 0; j < 8; j++) offs[tid * 8 + j] = pre + loc[j];
        if (tid == 255) offs[2048] = pre + s;    // == N
        return;
    }

    const int blk = blockIdx.x;              // 1024
    const int b   = blk >> 5;
    const int t0  = (blk & 31) * 64;
    const int n0  = b * T_ + t0;
    if (tid < 64) scode[tid] = idx[n0 + tid];
    __syncthreads();

    const float* zb = z    + (size_t)b * D_ * T_ + t0;
    float*       ob = out0 + (size_t)b * D_ * T_ + t0;
    float lsum = 0.0f;
#pragma unroll
    for (int it = 0; it < 8; it++) {
        int flat = it * 256 + tid;
        int d = flat >> 4;
        int q = flat & 15;
        float4 zv = *(const float4*)(zb + (size_t)d * T_ + q * 4);
        float zi[4] = {zv.x, zv.y, zv.z, zv.w};
        float ov[4];
#pragma unroll
        for (int j = 0; j < 4; j++) {
            int code = scode[q * 4 + j];
            float e  = emb[(size_t)code * D_ + d];
            float df = e - zi[j];            // z_vq - zf (one rounding)
            ov[j] = zi[j] + df;              // zf + (z_vq - zf), matches reference STE
            lsum += df * df;
        }
        float4 o4 = {ov[0], ov[1], ov[2], ov[3]};
        *(float4*)(ob + (size_t)d * T_ + q * 4) = o4;
    }

    red[tid] = lsum;
    __syncthreads();
    for (int s = 128; s > 0; s >>= 1) {
        if (tid < s) red[tid] += red[tid + s];
        __syncthreads();
    }
    if (tid == 0) atomicAdd(s_loss, red[0]);
}

__global__ void bucket_kernel(const int* __restrict__ idx, const int* __restrict__ pos,
                              const int* __restrict__ offs, int* __restrict__ row_list) {
    int n = blockIdx.x * 256 + threadIdx.x;
    row_list[offs[idx[n]] + pos[n]] = n;
}

// ---------------------------------------------------------------------------
// Segment sum, balanced by ROW: wave per 64 consecutive row_list entries
// (row_list is code-sorted). Lane l owns d-pair {2l, 2l+1}; wave walks its
// 64 rows via shfl broadcast (wave-uniform, no divergence), flushing the
// running partial to sum_new with 2 fp32 atomics/lane at code boundaries.
// ---------------------------------------------------------------------------
__global__ __launch_bounds__(64)
void segsum_kernel(const f16* __restrict__ zh, const f16* __restrict__ zl,
                   const int* __restrict__ row_list, const int* __restrict__ idx,
                   float* __restrict__ sum_new) {
    const int l = threadIdx.x;           // 64
    const int base = blockIdx.x * 64;    // 1024 blocks
    int myrow  = row_list[base + l];
    int mycode = idx[myrow];
    float ax = 0.0f, ay = 0.0f;
    int cur = __shfl(mycode, 0, 64);
#pragma unroll 8
    for (int i = 0; i < 64; i++) {
        int r = __shfl(myrow, i, 64);
        int c = __shfl(mycode, i, 64);
        if (c != cur) {                  // wave-uniform branch
            atomicAdd(&sum_new[(size_t)cur * D_ + l * 2],     ax);
            atomicAdd(&sum_new[(size_t)cur * D_ + l * 2 + 1], ay);
            ax = 0.0f; ay = 0.0f; cur = c;
        }
        f16x2 hv = *(const f16x2*)&zh[(size_t)r * D_ + l * 2];
        f16x2 lv = *(const f16x2*)&zl[(size_t)r * D_ + l * 2];
        ax += (float)hv.x + (float)lv.x;
        ay += (float)hv.y + (float)lv.y;
    }
    atomicAdd(&sum_new[(size_t)cur * D_ + l * 2],     ax);
    atomicAdd(&sum_new[(size_t)cur * D_ + l * 2 + 1], ay);
}

// ---------------------------------------------------------------------------
// EMA update, emb_new select, dk / entropy partial sums.
// elem_new derived from offs (counts) — no separate buffer.
// ---------------------------------------------------------------------------
__global__ __launch_bounds__(256)
void update_kernel(const float* __restrict__ emb, const float* __restrict__ emb_sum,
                   const float* __restrict__ emb_elem, const float* __restrict__ emb_rand,
                   const float* __restrict__ sum_new, const int* __restrict__ offs,
                   float* __restrict__ out_emb_new, float* __restrict__ out_emb_sum_n,
                   float* __restrict__ out_emb_elem_n,
                   float* __restrict__ s_ent, float* __restrict__ s_dk) {
    const float MU  = 0.99f;
    const float OMM = (float)(1.0 - 0.99);   // match JAX's fp64 1.0-0.99 -> fp32
    int gid = blockIdx.x * 256 + threadIdx.x;   // < K_*D_ = 262144
    int k = gid >> 7;
    int d = gid & 127;

    float sn = sum_new[gid];
    float es = emb_sum[gid];
    float en = (float)(offs[k + 1] - offs[k]);
    float ee = emb_elem[k];
    float esn = MU * es + OMM * sn;
    float een = MU * ee + OMM * en;
    out_emb_sum_n[gid] = esn;
    float enew = (een >= 1.0f) ? (esn / een) : emb_rand[gid];
    out_emb_new[gid] = enew;

    float df = enew - emb[gid];
    float v  = df * df;
    __shared__ float red[256];
    red[threadIdx.x] = v;
    __syncthreads();
    for (int s = 128; s > 0; s >>= 1) {
        if (threadIdx.x < s) red[threadIdx.x] += red[threadIdx.x + s];
        __syncthreads();
    }
    if (threadIdx.x == 0) atomicAdd(s_dk, red[0]);

    if (d == 0) {
        out_emb_elem_n[k] = een;
        float p = en * (1.0f / 65536.0f);   // sum(elem_new) == N exactly in fp32
        atomicAdd(s_ent, p * logf(p + 1e-8f));
    }
}

// ---------------------------------------------------------------------------
// Scalar finalization
// ---------------------------------------------------------------------------
__global__ void final_kernel(const float* __restrict__ s_loss, const float* __restrict__ s_ent,
                             const float* __restrict__ s_dk,
                             float* __restrict__ out_loss, float* __restrict__ out_ent,
                             float* __restrict__ out_dk) {
    out_loss[0] = s_loss[0];
    out_ent[0]  = expf(-s_ent[0]);
    out_dk[0]   = sqrtf(s_dk[0]) * (1.0f / 512.0f);   // sqrt(K*D) = 512
}

// ---------------------------------------------------------------------------
extern "C" void kernel_launch(void* const* d_in, const int* in_sizes, int n_in,
                              void* d_out, int out_size, void* d_ws, size_t ws_size,
                              hipStream_t stream) {
    (void)in_sizes; (void)n_in; (void)out_size; (void)ws_size;

    const float* z        = (const float*)d_in[0];   // [32,128,2048]
    const float* emb      = (const float*)d_in[1];   // [2048,128]
    const float* emb_sum  = (const float*)d_in[2];   // [2048,128]
    const float* emb_elem = (const float*)d_in[3];   // [2048]
    const float* emb_rand = (const float*)d_in[4];   // [2048,128]

    float* out = (float*)d_out;
    float* out0            = out;                            // z_vq_out  8388608
    float* out_loss        = out + 8388608;                  // scalar
    float* out_emb_new     = out + 8388609;                  // 262144
    float* out_emb_sum_n   = out + 8388609 + 262144;         // 262144
    float* out_emb_elem_n  = out + 8388609 + 524288;         // 2048
    float* out_ent         = out + 8388609 + 524288 + 2048;  // scalar
    float* out_dk          = out_ent + 1;                    // scalar

    float* ws = (float*)d_ws;                     // offsets in floats
    f16*   zh       = (f16*)(ws);                 // 8388608 halves (4194304 f)
    f16*   zl       = (f16*)(ws + 4194304);       // 8388608 halves
    int*   idx      = (int*)(ws + 8388608);       // 65536
    float* hn       = ws + 8454144;               // 2048
    f16*   eh       = (f16*)(ws + 8456192);       // 262144 halves (131072 f)
    f16*   el       = (f16*)(ws + 8587264);       // 262144 halves
    float* sum_new  = ws + 8718336;               // 262144
    int*   cnt      = (int*)(ws + 8980480);       // 2048
    float* scalars  = ws + 8982528;               // s_loss, s_ent, s_dk
    float* s_loss   = scalars;
    float* s_ent    = scalars + 1;
    float* s_dk     = scalars + 2;
    int*   pos      = (int*)(ws + 8982531);       // 65536
    int*   offs     = (int*)(ws + 9048067);       // 2049
    int*   row_list = (int*)(ws + 9050116);       // 65536
                                                  // end 9115652 f ~ 36.5 MB

    eprep_kernel<<<K_, 64, 0, stream>>>(emb, eh, el, hn, cnt, scalars, sum_new);
    prep_kernel<<<B_ * (T_ / 64), 256, 0, stream>>>(z, zh, zl);
    argmin_mfma<<<N_ / 64, 256, 0, stream>>>(zh, zl, eh, el, hn, idx, cnt, pos);
    ste_scan_kernel<<<B_ * (T_ / 64) + 1, 256, 0, stream>>>(z, emb, idx, out0, s_loss,
                                                            cnt, offs);
    bucket_kernel<<<N_ / 256, 256, 0, stream>>>(idx, pos, offs, row_list);
    segsum_kernel<<<N_ / 64, 64, 0, stream>>>(zh, zl, row_list, idx, sum_new);
    update_kernel<<<(K_ * D_) / 256, 256, 0, stream>>>(emb, emb_sum, emb_elem, emb_rand,
                                                       sum_new, offs,
                                                       out_emb_new, out_emb_sum_n,
                                                       out_emb_elem_n, s_ent, s_dk);
    final_kernel<<<1, 1, 0, stream>>>(s_loss, s_ent, s_dk, out_loss, out_ent, out_dk);
}

// Round 2
// 300.374 us; speedup vs baseline: 1.0513x; 1.0427x over previous
//
#include <hip/hip_runtime.h>
#include <float.h>
#include <math.h>

// Problem constants (from reference setup_inputs)
#define B_   32
#define D_   128
#define T_   2048
#define K_   2048
#define N_   (B_ * T_)      // 65536

typedef _Float16 f16;
typedef f16   f16x8 __attribute__((ext_vector_type(8)));
typedef f16   f16x4 __attribute__((ext_vector_type(4)));
typedef f16   f16x2 __attribute__((ext_vector_type(2)));
typedef float f32x4 __attribute__((ext_vector_type(4)));

// async global->LDS, 16 B per lane, LDS dst = wave-uniform base + lane*16
__device__ __forceinline__ void load_lds16(const void* g, void* l) {
    __builtin_amdgcn_global_load_lds(
        (const __attribute__((address_space(1))) unsigned int*)g,
        (__attribute__((address_space(3))) unsigned int*)l, 16, 0, 0);
}

// ---------------------------------------------------------------------------
// emb -> (eh, el) fp16 split + halfnorm. One wave per code.
// Also zeroes cnt[k], sum_new[k][:], and the 3 scalar accumulators.
// ---------------------------------------------------------------------------
__global__ void eprep_kernel(const float* __restrict__ emb, f16* __restrict__ eh,
                             f16* __restrict__ el, float* __restrict__ hn,
                             int* __restrict__ cnt, float* __restrict__ scalars,
                             float* __restrict__ sum_new) {
    int k = blockIdx.x;
    int l = threadIdx.x;            // 64
    if (l == 0) cnt[k] = 0;
    if (k == 0 && l < 3) scalars[l] = 0.0f;
    sum_new[(size_t)k * D_ + l]      = 0.0f;
    sum_new[(size_t)k * D_ + 64 + l] = 0.0f;
    float a = emb[(size_t)k * D_ + l];
    float b = emb[(size_t)k * D_ + 64 + l];
    f16 ah = (f16)a; f16 al = (f16)(a - (float)ah);
    f16 bh = (f16)b; f16 bl = (f16)(b - (float)bh);
    eh[(size_t)k * D_ + l]      = ah;
    eh[(size_t)k * D_ + 64 + l] = bh;
    el[(size_t)k * D_ + l]      = al;
    el[(size_t)k * D_ + 64 + l] = bl;
    float s = a * a + b * b;
#pragma unroll
    for (int off = 32; off > 0; off >>= 1) s += __shfl_down(s, off, 64);
    if (l == 0) hn[k] = 0.5f * s;
}

// ---------------------------------------------------------------------------
// z [B,D,T] -> row-major fp16 split zh[N][D], zl[N][D] (transpose via LDS)
// ---------------------------------------------------------------------------
__global__ __launch_bounds__(256)
void prep_kernel(const float* __restrict__ z, f16* __restrict__ zh, f16* __restrict__ zl) {
    __shared__ float tile[64][129];
    const int tid = threadIdx.x;
    const int blk = blockIdx.x;              // 1024
    const int b   = blk >> 5;
    const int t0  = (blk & 31) * 64;
    const int n0  = b * T_ + t0;
    const float* zb = z + (size_t)b * D_ * T_ + t0;
#pragma unroll
    for (int it = 0; it < 8; it++) {
        int flat = it * 256 + tid;           // 128 d x 16 q
        int d = flat >> 4;
        int q = flat & 15;
        float4 zv = *(const float4*)(zb + (size_t)d * T_ + q * 4);
        tile[q * 4 + 0][d] = zv.x;
        tile[q * 4 + 1][d] = zv.y;
        tile[q * 4 + 2][d] = zv.z;
        tile[q * 4 + 3][d] = zv.w;
    }
    __syncthreads();
#pragma unroll
    for (int it = 0; it < 8; it++) {
        int r  = it * 8 + (tid >> 5);
        int d0 = (tid & 31) * 4;
        f16x4 hv, lv;
#pragma unroll
        for (int j = 0; j < 4; j++) {
            float v = tile[r][d0 + j];
            f16 hh = (f16)v;
            f16 ll = (f16)(v - (float)hh);
            if (j == 0) { hv.x = hh; lv.x = ll; }
            if (j == 1) { hv.y = hh; lv.y = ll; }
            if (j == 2) { hv.z = hh; lv.z = ll; }
            if (j == 3) { hv.w = hh; lv.w = ll; }
        }
        *(f16x4*)&zh[(size_t)(n0 + r) * D_ + d0] = hv;
        *(f16x4*)&zl[(size_t)(n0 + r) * D_ + d0] = lv;
    }
}

// ---------------------------------------------------------------------------
// MFMA distance-argmin, pipelined, M_wave=64:
//   Block = 128 rows x all 2048 codes, 4 waves as 2M x 2N; each wave owns
//   64 rows x 32 codes of the current 64-code tile. A (zh+zl, 64 rows x
//   128 k) ENTIRELY in registers: 32 f16x8 = 128 VGPR, loaded once.
//   Doubling rows-per-wave doubles FLOP per B-byte: per tile per CU the
//   same 192 KB LDS traffic now feeds 2x the MFMA -> MFMA pipe (3090
//   cyc/SIMD/tile) > LDS pipe (~1700-2260) -> compute-bound structure.
//   B = 64-code tiles {eh, el} = 32 KB, double-buffered (64 KB LDS ->
//   2 blocks/CU; grid 512 = exactly 2/CU, single round, no tail).
//   Counted waits: vmcnt(8) keeps next tile's 8 stage loads in flight
//   across the barrier; never vmcnt(0) in the loop. T5 setprio around
//   MFMA clusters (2 desynced blocks/CU give the scheduler a role-split).
// ---------------------------------------------------------------------------
__global__ __launch_bounds__(256, 2)
void argmin_mfma(const f16* __restrict__ zh, const f16* __restrict__ zl,
                 const f16* __restrict__ eh, const f16* __restrict__ el,
                 const float* __restrict__ hn,
                 int* __restrict__ idx, int* __restrict__ cnt, int* __restrict__ pos) {
    __shared__ __align__(16) f16 BS[2][2][64 * 128];   // [buf][eh|el][code][k] = 64 KB

    const int tid = threadIdx.x;
    const int w   = tid >> 6;            // wave 0..3
    const int l   = tid & 63;
    const int wm  = w >> 1;              // M-half: rows wm*64..
    const int wn  = w & 1;               // N-half: codes wn*32.. of 64-code tile
    const int n0  = blockIdx.x * 128;    // 512 blocks
    const int c15 = l & 15;
    const int q   = l >> 4;

    // ---- prologue: hn(tile0) -> regs, stage tile0, A -> regs ----
    float hc0 = hn[wn * 32 + c15];
    float hc1 = hn[wn * 32 + 16 + c15];

    {   // stage tile 0 into buf 0 (8 load_lds16/wave; XOR-16 swizzled source)
#pragma unroll
        for (int i = 0; i < 4; i++) {
            int cl = w * 16 + i * 4 + q;
            int g  = c15 ^ (cl & 15);
            load_lds16(eh + (size_t)cl * D_ + g * 8, &BS[0][0][(w * 16 + i * 4) * 128]);
            load_lds16(el + (size_t)cl * D_ + g * 8, &BS[0][1][(w * 16 + i * 4) * 128]);
        }
    }

    // A fragments: row = n0 + wm*64 + mi*16 + c15, k = s*32 + q*8 + j
    f16x8 azh[4][4], azl[4][4];
#pragma unroll
    for (int mi = 0; mi < 4; mi++)
#pragma unroll
        for (int s = 0; s < 4; s++) {
            size_t off = (size_t)(n0 + wm * 64 + mi * 16 + c15) * D_ + s * 32 + q * 8;
            azh[mi][s] = *(const f16x8*)&zh[off];
            azl[mi][s] = *(const f16x8*)&zl[off];
        }

    float minv[4][4];
    int   mini[4][4];
#pragma unroll
    for (int mi = 0; mi < 4; mi++)
#pragma unroll
        for (int r = 0; r < 4; r++) { minv[mi][r] = FLT_MAX; mini[mi][r] = 0x7fffffff; }

    for (int t = 0; t < 32; t++) {
        const int cur = t & 1;
        float hp0 = 0.0f, hp1 = 0.0f;
        if (t < 31) {
            // hn prefetch FIRST (older than the stage loads -> covered by vmcnt(8))
            hp0 = hn[(t + 1) * 64 + wn * 32 + c15];
            hp1 = hn[(t + 1) * 64 + wn * 32 + 16 + c15];
#pragma unroll
            for (int i = 0; i < 4; i++) {
                int cl = w * 16 + i * 4 + q;
                int g  = c15 ^ (cl & 15);
                load_lds16(eh + ((size_t)(t + 1) * 64 + cl) * D_ + g * 8,
                           &BS[cur ^ 1][0][(w * 16 + i * 4) * 128]);
                load_lds16(el + ((size_t)(t + 1) * 64 + cl) * D_ + g * 8,
                           &BS[cur ^ 1][1][(w * 16 + i * 4) * 128]);
            }
            // tile t's 8 loads (+ hn + A on t==0) done; tile t+1's 8 stay in flight
            asm volatile("s_waitcnt vmcnt(8)" ::: "memory");
        } else {
            asm volatile("s_waitcnt vmcnt(0)" ::: "memory");
        }
        __builtin_amdgcn_s_barrier();
        asm volatile("" ::: "memory");   // keep ds_reads below the barrier

        f32x4 acc[4][2];
#pragma unroll
        for (int mi = 0; mi < 4; mi++)
#pragma unroll
            for (int ni = 0; ni < 2; ni++) acc[mi][ni] = (f32x4){0.f, 0.f, 0.f, 0.f};

        const f16* __restrict__ BH = &BS[cur][0][0];
        const f16* __restrict__ BL = &BS[cur][1][0];
#pragma unroll
        for (int s = 0; s < 4; s++) {
            const int gp = (s * 4 + q) ^ c15;
            f16x8 bh[2], bl[2];
#pragma unroll
            for (int ni = 0; ni < 2; ni++) {
                int n = wn * 32 + ni * 16 + c15;
                bh[ni] = *(const f16x8*)&BH[n * 128 + gp * 8];
                bl[ni] = *(const f16x8*)&BL[n * 128 + gp * 8];
            }
            __builtin_amdgcn_s_setprio(1);
#pragma unroll
            for (int mi = 0; mi < 4; mi++)
#pragma unroll
                for (int ni = 0; ni < 2; ni++) {
                    acc[mi][ni] = __builtin_amdgcn_mfma_f32_16x16x32_f16(
                        azh[mi][s], bh[ni], acc[mi][ni], 0, 0, 0);
                    acc[mi][ni] = __builtin_amdgcn_mfma_f32_16x16x32_f16(
                        azl[mi][s], bh[ni], acc[mi][ni], 0, 0, 0);
                    acc[mi][ni] = __builtin_amdgcn_mfma_f32_16x16x32_f16(
                        azh[mi][s], bl[ni], acc[mi][ni], 0, 0, 0);
                }
            __builtin_amdgcn_s_setprio(0);
        }

        // ---- running argmin (codes ascend: t, ni ascending; strict <) ----
        const int k0 = t * 64;
#pragma unroll
        for (int ni = 0; ni < 2; ni++) {
            int   k = k0 + wn * 32 + ni * 16 + c15;
            float h = ni ? hc1 : hc0;
#pragma unroll
            for (int mi = 0; mi < 4; mi++)
#pragma unroll
                for (int r = 0; r < 4; r++) {
                    float sc = h - acc[mi][ni][r];
                    if (sc < minv[mi][r]) { minv[mi][r] = sc; mini[mi][r] = k; }
                }
        }
        hc0 = hp0; hc1 = hp1;

        asm volatile("" ::: "memory");   // keep ds_reads above this barrier
        __builtin_amdgcn_s_barrier();    // buf[cur] free for overwrite next iter
    }

    // ---- single epilogue: cross-lane reduce, write idx + count atomic ----
    __syncthreads();                     // full drain once; alias BS as red
    float* redv = (float*)&BS[0][0][0];  // [128][2]
    int*   redi = (int*)&BS[0][1][0];
#pragma unroll
    for (int mi = 0; mi < 4; mi++)
#pragma unroll
        for (int r = 0; r < 4; r++) {
            float bv = minv[mi][r];
            int   bi = mini[mi][r];
#pragma unroll
            for (int msk = 1; msk < 16; msk <<= 1) {
                float ov = __shfl_xor(bv, msk, 64);
                int   oi = __shfl_xor(bi, msk, 64);
                if (ov < bv || (ov == bv && oi < bi)) { bv = ov; bi = oi; }
            }
            if (c15 == 0) {
                int row = wm * 64 + mi * 16 + q * 4 + r;
                redv[row * 2 + wn] = bv;
                redi[row * 2 + wn] = bi;
            }
        }
    __syncthreads();
    if (tid < 128) {
        float v0 = redv[tid * 2 + 0]; int i0 = redi[tid * 2 + 0];
        float v1 = redv[tid * 2 + 1]; int i1 = redi[tid * 2 + 1];
        if (v1 < v0 || (v1 == v0 && i1 < i0)) { v0 = v1; i0 = i1; }
        int n = n0 + tid;
        idx[n] = i0;
        pos[n] = atomicAdd(&cnt[i0], 1);     // fused assign_kernel
    }
}

// ---------------------------------------------------------------------------
// STE output + loss (blocks 0..1023) with the single-block prefix-scan fused
// as block 1024 (removes the whole-GPU-idle scan launch). Scan only needs
// cnt (argmin done); ste only needs idx.
// ---------------------------------------------------------------------------
__global__ __launch_bounds__(256)
void ste_scan_kernel(const float* __restrict__ z, const float* __restrict__ emb,
                     const int* __restrict__ idx, float* __restrict__ out0,
                     float* __restrict__ s_loss,
                     const int* __restrict__ cnt, int* __restrict__ offs) {
    __shared__ int   scode[64];
    __shared__ float red[256];
    __shared__ int   part[256];
    const int tid = threadIdx.x;

    if (blockIdx.x == 1024) {            // ---- fused exclusive prefix scan ----
        int loc[8];
        int s = 0;
#pragma unroll
        for (int j = 0; j < 8; j++) { loc[j] = s; s += cnt[tid * 8 + j]; }
        part[tid] = s;
        __syncthreads();
        for (int off = 1; off < 256; off <<= 1) {
            int v = (tid >= off) ? part[tid - off] : 0;
            __syncthreads();
            part[tid] += v;
            __syncthreads();
        }
        int pre = (tid == 0) ? 0 : part[tid - 1];
#pragma unroll
        for (int j = 0; j < 8; j++) offs[tid * 8 + j] = pre + loc[j];
        if (tid == 255) offs[2048] = pre + s;    // == N
        return;
    }

    const int blk = blockIdx.x;              // 1024
    const int b   = blk >> 5;
    const int t0  = (blk & 31) * 64;
    const int n0  = b * T_ + t0;
    if (tid < 64) scode[tid] = idx[n0 + tid];
    __syncthreads();

    const float* zb = z    + (size_t)b * D_ * T_ + t0;
    float*       ob = out0 + (size_t)b * D_ * T_ + t0;
    float lsum = 0.0f;
#pragma unroll
    for (int it = 0; it < 8; it++) {
        int flat = it * 256 + tid;
        int d = flat >> 4;
        int q = flat & 15;
        float4 zv = *(const float4*)(zb + (size_t)d * T_ + q * 4);
        float zi[4] = {zv.x, zv.y, zv.z, zv.w};
        float ov[4];
#pragma unroll
        for (int j = 0; j < 4; j++) {
            int code = scode[q * 4 + j];
            float e  = emb[(size_t)code * D_ + d];
            float df = e - zi[j];            // z_vq - zf (one rounding)
            ov[j] = zi[j] + df;              // zf + (z_vq - zf), matches reference STE
            lsum += df * df;
        }
        float4 o4 = {ov[0], ov[1], ov[2], ov[3]};
        *(float4*)(ob + (size_t)d * T_ + q * 4) = o4;
    }

    red[tid] = lsum;
    __syncthreads();
    for (int s = 128; s > 0; s >>= 1) {
        if (tid < s) red[tid] += red[tid + s];
        __syncthreads();
    }
    if (tid == 0) atomicAdd(s_loss, red[0]);
}

__global__ void bucket_kernel(const int* __restrict__ idx, const int* __restrict__ pos,
                              const int* __restrict__ offs, int* __restrict__ row_list) {
    int n = blockIdx.x * 256 + threadIdx.x;
    row_list[offs[idx[n]] + pos[n]] = n;
}

// ---------------------------------------------------------------------------
// Segment sum, balanced by ROW: wave per 64 consecutive row_list entries
// (row_list is code-sorted). Lane l owns d-pair {2l, 2l+1}; wave walks its
// 64 rows via shfl broadcast (wave-uniform, no divergence), flushing the
// running partial to sum_new with 2 fp32 atomics/lane at code boundaries.
// ---------------------------------------------------------------------------
__global__ __launch_bounds__(64)
void segsum_kernel(const f16* __restrict__ zh, const f16* __restrict__ zl,
                   const int* __restrict__ row_list, const int* __restrict__ idx,
                   float* __restrict__ sum_new) {
    const int l = threadIdx.x;           // 64
    const int base = blockIdx.x * 64;    // 1024 blocks
    int myrow  = row_list[base + l];
    int mycode = idx[myrow];
    float ax = 0.0f, ay = 0.0f;
    int cur = __shfl(mycode, 0, 64);
#pragma unroll 8
    for (int i = 0; i < 64; i++) {
        int r = __shfl(myrow, i, 64);
        int c = __shfl(mycode, i, 64);
        if (c != cur) {                  // wave-uniform branch
            atomicAdd(&sum_new[(size_t)cur * D_ + l * 2],     ax);
            atomicAdd(&sum_new[(size_t)cur * D_ + l * 2 + 1], ay);
            ax = 0.0f; ay = 0.0f; cur = c;
        }
        f16x2 hv = *(const f16x2*)&zh[(size_t)r * D_ + l * 2];
        f16x2 lv = *(const f16x2*)&zl[(size_t)r * D_ + l * 2];
        ax += (float)hv.x + (float)lv.x;
        ay += (float)hv.y + (float)lv.y;
    }
    atomicAdd(&sum_new[(size_t)cur * D_ + l * 2],     ax);
    atomicAdd(&sum_new[(size_t)cur * D_ + l * 2 + 1], ay);
}

// ---------------------------------------------------------------------------
// EMA update, emb_new select, dk / entropy partial sums.
// elem_new derived from offs (counts) — no separate buffer.
// ---------------------------------------------------------------------------
__global__ __launch_bounds__(256)
void update_kernel(const float* __restrict__ emb, const float* __restrict__ emb_sum,
                   const float* __restrict__ emb_elem, const float* __restrict__ emb_rand,
                   const float* __restrict__ sum_new, const int* __restrict__ offs,
                   float* __restrict__ out_emb_new, float* __restrict__ out_emb_sum_n,
                   float* __restrict__ out_emb_elem_n,
                   float* __restrict__ s_ent, float* __restrict__ s_dk) {
    const float MU  = 0.99f;
    const float OMM = (float)(1.0 - 0.99);   // match JAX's fp64 1.0-0.99 -> fp32
    int gid = blockIdx.x * 256 + threadIdx.x;   // < K_*D_ = 262144
    int k = gid >> 7;
    int d = gid & 127;

    float sn = sum_new[gid];
    float es = emb_sum[gid];
    float en = (float)(offs[k + 1] - offs[k]);
    float ee = emb_elem[k];
    float esn = MU * es + OMM * sn;
    float een = MU * ee + OMM * en;
    out_emb_sum_n[gid] = esn;
    float enew = (een >= 1.0f) ? (esn / een) : emb_rand[gid];
    out_emb_new[gid] = enew;

    float df = enew - emb[gid];
    float v  = df * df;
    __shared__ float red[256];
    red[threadIdx.x] = v;
    __syncthreads();
    for (int s = 128; s > 0; s >>= 1) {
        if (threadIdx.x < s) red[threadIdx.x] += red[threadIdx.x + s];
        __syncthreads();
    }
    if (threadIdx.x == 0) atomicAdd(s_dk, red[0]);

    if (d == 0) {
        out_emb_elem_n[k] = een;
        float p = en * (1.0f / 65536.0f);   // sum(elem_new) == N exactly in fp32
        atomicAdd(s_ent, p * logf(p + 1e-8f));
    }
}

// ---------------------------------------------------------------------------
// Scalar finalization
// ---------------------------------------------------------------------------
__global__ void final_kernel(const float* __restrict__ s_loss, const float* __restrict__ s_ent,
                             const float* __restrict__ s_dk,
                             float* __restrict__ out_loss, float* __restrict__ out_ent,
                             float* __restrict__ out_dk) {
    out_loss[0] = s_loss[0];
    out_ent[0]  = expf(-s_ent[0]);
    out_dk[0]   = sqrtf(s_dk[0]) * (1.0f / 512.0f);   // sqrt(K*D) = 512
}

// ---------------------------------------------------------------------------
extern "C" void kernel_launch(void* const* d_in, const int* in_sizes, int n_in,
                              void* d_out, int out_size, void* d_ws, size_t ws_size,
                              hipStream_t stream) {
    (void)in_sizes; (void)n_in; (void)out_size; (void)ws_size;

    const float* z        = (const float*)d_in[0];   // [32,128,2048]
    const float* emb      = (const float*)d_in[1];   // [2048,128]
    const float* emb_sum  = (const float*)d_in[2];   // [2048,128]
    const float* emb_elem = (const float*)d_in[3];   // [2048]
    const float* emb_rand = (const float*)d_in[4];   // [2048,128]

    float* out = (float*)d_out;
    float* out0            = out;                            // z_vq_out  8388608
    float* out_loss        = out + 8388608;                  // scalar
    float* out_emb_new     = out + 8388609;                  // 262144
    float* out_emb_sum_n   = out + 8388609 + 262144;         // 262144
    float* out_emb_elem_n  = out + 8388609 + 524288;         // 2048
    float* out_ent         = out + 8388609 + 524288 + 2048;  // scalar
    float* out_dk          = out_ent + 1;                    // scalar

    float* ws = (float*)d_ws;                     // offsets in floats
    f16*   zh       = (f16*)(ws);                 // 8388608 halves (4194304 f)
    f16*   zl       = (f16*)(ws + 4194304);       // 8388608 halves
    int*   idx      = (int*)(ws + 8388608);       // 65536
    float* hn       = ws + 8454144;               // 2048
    f16*   eh       = (f16*)(ws + 8456192);       // 262144 halves (131072 f)
    f16*   el       = (f16*)(ws + 8587264);       // 262144 halves
    float* sum_new  = ws + 8718336;               // 262144
    int*   cnt      = (int*)(ws + 8980480);       // 2048
    float* scalars  = ws + 8982528;               // s_loss, s_ent, s_dk
    float* s_loss   = scalars;
    float* s_ent    = scalars + 1;
    float* s_dk     = scalars + 2;
    int*   pos      = (int*)(ws + 8982531);       // 65536
    int*   offs     = (int*)(ws + 9048067);       // 2049
    int*   row_list = (int*)(ws + 9050116);       // 65536
                                                  // end 9115652 f ~ 36.5 MB

    eprep_kernel<<<K_, 64, 0, stream>>>(emb, eh, el, hn, cnt, scalars, sum_new);
    prep_kernel<<<B_ * (T_ / 64), 256, 0, stream>>>(z, zh, zl);
    argmin_mfma<<<N_ / 128, 256, 0, stream>>>(zh, zl, eh, el, hn, idx, cnt, pos);
    ste_scan_kernel<<<B_ * (T_ / 64) + 1, 256, 0, stream>>>(z, emb, idx, out0, s_loss,
                                                            cnt, offs);
    bucket_kernel<<<N_ / 256, 256, 0, stream>>>(idx, pos, offs, row_list);
    segsum_kernel<<<N_ / 64, 64, 0, stream>>>(zh, zl, row_list, idx, sum_new);
    update_kernel<<<(K_ * D_) / 256, 256, 0, stream>>>(emb, emb_sum, emb_elem, emb_rand,
                                                       sum_new, offs,
                                                       out_emb_new, out_emb_sum_n,
                                                       out_emb_elem_n, s_ent, s_dk);
    final_kernel<<<1, 1, 0, stream>>>(s_loss, s_ent, s_dk, out_loss, out_ent, out_dk);
}